// Round 4
// baseline (275.865 us; speedup 1.0000x reference)
//
#include <hip/hip_runtime.h>
#include <hip/hip_bf16.h>

typedef __bf16 bf16_t;
typedef __attribute__((ext_vector_type(8))) __bf16 bfrag;   // 8 bf16 = 4 VGPRs (MFMA A/B frag)
typedef __attribute__((ext_vector_type(4))) __bf16 bf16x4;  // 8B packed store
typedef __attribute__((ext_vector_type(4))) float f32x4;    // MFMA C/D frag

#define SEQ    4096
#define NDIM   1024
#define NHEAD  16
#define HD     64
#define NBATCH 2
#define MROWS  (NBATCH * SEQ)   // 8192
#define LQK    2048             // fused Q|K row stride
#define PSTR   76               // Pw key-stride (conflict-free b64 writes, verified R7-R10)

// async 16B global -> LDS (m97 pattern). l must be wave-uniform; lane i lands at l + i*16.
__device__ __forceinline__ void gload_lds16(const bf16_t* g, bf16_t* l) {
    __builtin_amdgcn_global_load_lds(
        (const __attribute__((address_space(1))) unsigned int*)g,
        (__attribute__((address_space(3))) unsigned int*)l,
        16, 0, 0);
}

// raw workgroup barrier WITHOUT the vmcnt(0)/lgkmcnt(0) drain of __syncthreads.
// memory clobbers pin placement of LDS reads / DMA issues to their phase.
#define BAR()  do { asm volatile("" ::: "memory"); __builtin_amdgcn_s_barrier(); \
                    asm volatile("" ::: "memory"); } while (0)
#define VMC(n)  asm volatile("s_waitcnt vmcnt(" #n ")" ::: "memory")

// ---------------------------------------------------------------------------
// 256x256 8-phase GEMM, R4: fragment reads software-pipelined ONE PHASE EARLY
// (the m201 "lgkmcnt(8) if 12 ds_reads this phase" mechanism). No explicit
// lgkmcnt — the compiler inserts exact counted waits before MFMA uses (m97
// asm evidence), which are now non-zero because each phase's frags were
// issued a phase ahead. This lets the LDS pipe service phase p+1's reads
// while the matrix pipe crunches phase p's 16 MFMA (R3's lgkmcnt(0)
// serialized them -> 25% MfmaUtil).
// Geometry (same as R3, correctness-verified): 512 thr / 8 waves (2Mx4N),
// per-wave 128x64 out, BK=64, slots = 8 x 16 KiB = 128 KiB dynamic LDS,
// slot(d,op,h) = d*32768 + op*16384 + h*8192 els (d=step parity, op 0=A 1=B,
// h=K-half of 32). Swizzle byte ^= ((byte>>9)&1)<<5 on pre-swizzled global
// source + ds_read addr (0 conflicts, R1/R3 PMC).
// Phase layout per step s (d=s&1):
//   ph1: rd a_hi0<-(d,0,0);            st A-k1(s+1)->(d^1,0,1); B; MFMA aL0xb0; B
//   ph2: rd a_lo1<-(d,0,1), b1<-(d,1,1); st B-k0(s+2)->(d,1,0); B; MFMA aH0xb0; VMC; B
//   ph3: rd a_hi1<-(d,0,1);            st A-k0(s+2)->(d,0,0);  B; MFMA aL1xb1; B
//   ph4: rd next a_lo0,b0<-(d^1,*,0);  st B-k1(s+2)->(d,1,1);  B; MFMA aH1xb1; VMC; B
// vmcnt ledger (2 loads/half-tile), guards READ-ISSUE of staged data:
//   ph2(s) guards ph4(s) reads of A-k0(s+1)@ph3(s-1),B-k0(s+1)@ph2(s-1):
//     outstanding after = B-k1(s+1),A-k1(s+1),B-k0(s+2) = 3 half = vmcnt(6);
//     tail: s=NT-2 -> 4 (B-k0(NT) skipped), s=NT-1 -> 0.
//   ph4(s) guards ph2(s+1) reads of A-k1(s+1)@ph1(s),B-k1(s+1)@ph4(s-1):
//     outstanding after = B-k0(s+2),A-k0(s+2),B-k1(s+2) = 3 half = vmcnt(6);
//     tail: s=NT-2 -> 0, s=NT-1 -> skip.
//   prologue: 7 half-tiles issued, vmcnt(6) guarantees H1..H4 (= step0 A,B
//     both K-halves) before the pre-loop reads.
// Slot WAR (stage vs prior reads, all waves): each stage dest's last read
// issues >=1 phase earlier; its counted wait precedes that phase's MFMA and
// the intervening barrier publishes completion. Audited per-slot.
// ---------------------------------------------------------------------------
__global__ __launch_bounds__(512, 2)
void gemm256(const bf16_t* __restrict__ A, int lda,
             const bf16_t* __restrict__ W,
             const float* __restrict__ b0p, const float* __restrict__ b1p,
             const float* __restrict__ b2p, float qscale,
             bf16_t* __restrict__ C, int ldc, int K,
             bf16_t* __restrict__ VtOut)
{
    extern __shared__ bf16_t LDS[];   // 65536 els = 128 KiB

    const int tid  = threadIdx.x;
    const int lane = tid & 63;
    const int n16  = lane & 15;
    const int quad = lane >> 4;
    const int wid  = tid >> 6;
    const int wm   = wid >> 2;            // 0..1
    const int wn   = wid & 3;             // 0..3
    const int row0 = blockIdx.y * 256;
    const int col0 = blockIdx.x * 256;
    const int NT   = K >> 6;              // K-steps of 64 (NT >= 3)

    // per-thread staging source map (sub in {0,1} = 8KB halves of a 16KB slot)
    int poff0 = tid * 16;
    int loff0 = poff0 ^ (((poff0 >> 9) & 1) << 5);
    int poff1 = 8192 + tid * 16;
    int loff1 = poff1 ^ (((poff1 >> 9) & 1) << 5);
    const int r0 = loff0 >> 6, c0 = (loff0 & 63) >> 1;   // rows 0..127
    const int r1 = loff1 >> 6, c1 = (loff1 & 63) >> 1;   // rows 128..255
    const bf16_t* Asrc0 = A + (size_t)(row0 + r0) * lda + c0;
    const bf16_t* Asrc1 = A + (size_t)(row0 + r1) * lda + c1;
    const bf16_t* Wsrc0 = W + (size_t)(col0 + r0) * K + c0;
    const bf16_t* Wsrc1 = W + (size_t)(col0 + r1) * K + c1;
    bf16_t* const dst0 = LDS;
    const int wb = wid * 512;

    f32x4 acc[8][4];
#pragma unroll
    for (int m = 0; m < 8; m++)
#pragma unroll
        for (int j = 0; j < 4; j++) acc[m][j] = (f32x4){0.f, 0.f, 0.f, 0.f};

#define SLOT(d, op, h) ((d) * 32768 + (op) * 16384 + (h) * 8192)
#define STAGE(srcA0, srcA1, slot, gk)                                   \
    do { gload_lds16((srcA0) + (gk), dst0 + (slot) + wb);               \
         gload_lds16((srcA1) + (gk), dst0 + (slot) + 4096 + wb); } while (0)
// read 4 A- or B-frags at rows rbase..rbase+3*16 from a slot (swizzled)
#define RD4(dst, slot, rbase)                                           \
    do { _Pragma("unroll")                                              \
        for (int f = 0; f < 4; f++) {                                   \
            int off = (((rbase) + f * 16 + n16) << 6) + (quad << 4);    \
            off ^= ((off >> 9) & 1) << 5;                               \
            dst[f] = *(const bfrag*)((const char*)(LDS + (slot)) + off);\
        } } while (0)

    bfrag aL0[4], aH0[4], aL1[4], aH1[4], b0f[4], b1f[4];

    // ---- prologue: 7 half-tiles in consumption order ----
    STAGE(Wsrc0, Wsrc1, SLOT(0,1,0), 0);     // H1 B-k0(0)
    STAGE(Asrc0, Asrc1, SLOT(0,0,0), 0);     // H2 A-k0(0)
    STAGE(Wsrc0, Wsrc1, SLOT(0,1,1), 32);    // H3 B-k1(0)
    STAGE(Asrc0, Asrc1, SLOT(0,0,1), 32);    // H4 A-k1(0)
    STAGE(Wsrc0, Wsrc1, SLOT(1,1,0), 64);    // H5 B-k0(1)
    STAGE(Asrc0, Asrc1, SLOT(1,0,0), 64);    // H6 A-k0(1)
    STAGE(Wsrc0, Wsrc1, SLOT(1,1,1), 96);    // H7 B-k1(1)
    VMC(6);                                  // H1..H4 landed (step 0 complete)
    BAR();
    RD4(aL0, SLOT(0,0,0), wm * 128);         // pre-read ph1(0) frags
    RD4(b0f, SLOT(0,1,0), wn * 64);

    for (int s = 0; s < NT; ++s) {
        const int d = s & 1;

        // ================= ph1: MFMA aL0 x b0 (m-lo, k0) =================
        RD4(aH0, SLOT(d, 0, 0), wm * 128 + 64);              // for ph2
        if (s + 1 < NT) STAGE(Asrc0, Asrc1, SLOT(d ^ 1, 0, 1), (s + 1) * 64 + 32);
        BAR();
        __builtin_amdgcn_s_setprio(1);
#pragma unroll
        for (int f = 0; f < 4; f++)
#pragma unroll
            for (int j = 0; j < 4; j++)
                acc[f][j] = __builtin_amdgcn_mfma_f32_16x16x32_bf16(aL0[f], b0f[j], acc[f][j], 0, 0, 0);
        __builtin_amdgcn_s_setprio(0);
        BAR();

        // ================= ph2: MFMA aH0 x b0 (m-hi, k0) =================
        RD4(aL1, SLOT(d, 0, 1), wm * 128);                   // for ph3
        RD4(b1f, SLOT(d, 1, 1), wn * 64);
        if (s + 2 < NT) STAGE(Wsrc0, Wsrc1, SLOT(d, 1, 0), (s + 2) * 64);
        BAR();
        __builtin_amdgcn_s_setprio(1);
#pragma unroll
        for (int f = 0; f < 4; f++)
#pragma unroll
            for (int j = 0; j < 4; j++)
                acc[f + 4][j] = __builtin_amdgcn_mfma_f32_16x16x32_bf16(aH0[f], b0f[j], acc[f + 4][j], 0, 0, 0);
        __builtin_amdgcn_s_setprio(0);
        if (s < NT - 2)       VMC(6);
        else if (s == NT - 2) VMC(4);
        else                  VMC(0);
        BAR();

        // ================= ph3: MFMA aL1 x b1 (m-lo, k1) =================
        RD4(aH1, SLOT(d, 0, 1), wm * 128 + 64);              // for ph4
        if (s + 2 < NT) STAGE(Asrc0, Asrc1, SLOT(d, 0, 0), (s + 2) * 64);
        BAR();
        __builtin_amdgcn_s_setprio(1);
#pragma unroll
        for (int f = 0; f < 4; f++)
#pragma unroll
            for (int j = 0; j < 4; j++)
                acc[f][j] = __builtin_amdgcn_mfma_f32_16x16x32_bf16(aL1[f], b1f[j], acc[f][j], 0, 0, 0);
        __builtin_amdgcn_s_setprio(0);
        BAR();

        // ================= ph4: MFMA aH1 x b1 (m-hi, k1) =================
        if (s + 1 < NT) {                                    // next step's ph1 frags
            RD4(aL0, SLOT(d ^ 1, 0, 0), wm * 128);
            RD4(b0f, SLOT(d ^ 1, 1, 0), wn * 64);
        }
        if (s + 2 < NT) STAGE(Wsrc0, Wsrc1, SLOT(d, 1, 1), (s + 2) * 64 + 32);
        BAR();
        __builtin_amdgcn_s_setprio(1);
#pragma unroll
        for (int f = 0; f < 4; f++)
#pragma unroll
            for (int j = 0; j < 4; j++)
                acc[f + 4][j] = __builtin_amdgcn_mfma_f32_16x16x32_bf16(aH1[f], b1f[j], acc[f + 4][j], 0, 0, 0);
        __builtin_amdgcn_s_setprio(0);
        if (s < NT - 2)       VMC(6);
        else if (s == NT - 2) VMC(0);
        BAR();
    }
#undef STAGE
#undef SLOT
#undef RD4

    // ---- epilogue ----
    const float* bias = (col0 < 1024) ? b0p : (col0 < 2048 ? b1p : b2p);
    const float bsc   = (col0 < 1024) ? qscale : 1.0f;
    const int bcol0   = col0 & 1023;

    if (col0 < 2048 || VtOut == nullptr) {
#pragma unroll
        for (int m = 0; m < 8; m++)
#pragma unroll
            for (int j = 0; j < 4; j++)
#pragma unroll
                for (int r = 0; r < 4; r++) {
                    int row = row0 + wm * 128 + m * 16 + quad * 4 + r;
                    int col = wn * 64 + j * 16 + n16;
                    float v = acc[m][j][r] + bias[bcol0 + col] * bsc;
                    C[(size_t)row * ldc + col0 + col] = (bf16_t)v;
                }
    } else {
        // V block: write transposed into Vt[(b*16+h)*64+d][s], packed 4 tokens
#pragma unroll
        for (int m = 0; m < 8; m++) {
#pragma unroll
            for (int j = 0; j < 4; j++) {
                int dg     = col0 + wn * 64 + j * 16 + n16 - 2048;   // 0..1023
                int token0 = row0 + wm * 128 + m * 16 + quad * 4;
                int bb     = token0 >> 12;
                float bv   = bias[bcol0 + wn * 64 + j * 16 + n16];
                size_t vrow = ((size_t)bb * NHEAD + (dg >> 6)) * HD + (dg & 63);
                bf16x4 pk;
#pragma unroll
                for (int r = 0; r < 4; r++) pk[r] = (__bf16)(acc[m][j][r] + bv);
                *(bf16x4*)&VtOut[vrow * SEQ + (token0 & (SEQ - 1))] = pk;
            }
        }
    }
}

// ---------------------------------------------------------------------------
// GEMM: C[M,N] = A[M,K] @ W[N,K]^T + bias   (bf16 in, f32 acc, OT out)
// m97 structure: 128x128 tile, BK=32. Used for the O-projection (N=1024 ->
// 512 blocks fills all CUs) and as the QKV fallback if dynamic-LDS fails.
// ---------------------------------------------------------------------------
template <typename OT>
__global__ __launch_bounds__(256, 2)
void gemm_bt(const bf16_t* __restrict__ A, int lda,
             const bf16_t* __restrict__ W,
             const float* __restrict__ b0p, const float* __restrict__ b1p,
             const float* __restrict__ b2p, float qscale,
             OT* __restrict__ C, int ldc, int K,
             bf16_t* __restrict__ VtOut)
{
    __shared__ __align__(16) bf16_t As[128 * 32];
    __shared__ __align__(16) bf16_t Bs[128 * 32];

    const int tid  = threadIdx.x;
    const int lane = tid & 63;
    const int wid  = tid >> 6;
    const int n16  = lane & 15;
    const int quad = lane >> 4;
    const int row0 = blockIdx.y * 128;
    const int col0 = blockIdx.x * 128;
    const int wrow = (wid >> 1) * 64;
    const int wcol = (wid & 1) * 64;
    const float* bias = (col0 < 1024) ? b0p : (col0 < 2048 ? b1p : b2p);
    const float bsc = (col0 < 1024) ? qscale : 1.0f;
    const int bcol0 = col0 & 1023;

    f32x4 acc[4][4];
#pragma unroll
    for (int i = 0; i < 4; i++)
#pragma unroll
        for (int j = 0; j < 4; j++) acc[i][j] = (f32x4){0.f, 0.f, 0.f, 0.f};

    for (int k0 = 0; k0 < K; k0 += 32) {
#pragma unroll
        for (int it = 0; it < 2; it++) {
            int idx = tid + it * 256;          // 16B-chunk index 0..511
            int r   = idx >> 2;
            int c   = (idx & 3) * 8;
            gload_lds16(A + (size_t)(row0 + r) * lda + k0 + c, &As[(it * 256 + wid * 64) * 8]);
            gload_lds16(W + (size_t)(col0 + r) * K   + k0 + c, &Bs[(it * 256 + wid * 64) * 8]);
        }
        __syncthreads();

        bfrag af[4], bfg[4];
#pragma unroll
        for (int i = 0; i < 4; i++)
            af[i] = *(const bfrag*)(&As[(wrow + i * 16 + n16) * 32 + quad * 8]);
#pragma unroll
        for (int j = 0; j < 4; j++)
            bfg[j] = *(const bfrag*)(&Bs[(wcol + j * 16 + n16) * 32 + quad * 8]);

#pragma unroll
        for (int i = 0; i < 4; i++)
#pragma unroll
            for (int j = 0; j < 4; j++)
                acc[i][j] = __builtin_amdgcn_mfma_f32_16x16x32_bf16(af[i], bfg[j], acc[i][j], 0, 0, 0);
        __syncthreads();
    }

    if (col0 < 2048 || VtOut == nullptr) {
#pragma unroll
        for (int i = 0; i < 4; i++)
#pragma unroll
            for (int j = 0; j < 4; j++)
#pragma unroll
                for (int r = 0; r < 4; r++) {
                    int row = row0 + wrow + i * 16 + quad * 4 + r;
                    int col = wcol + j * 16 + n16;
                    float v = acc[i][j][r] + bias[bcol0 + col] * bsc;
                    C[(size_t)row * ldc + col0 + col] = (OT)v;
                }
    } else {
#pragma unroll
        for (int i = 0; i < 4; i++) {
#pragma unroll
            for (int j = 0; j < 4; j++) {
                int dg     = col0 + wcol + j * 16 + n16 - 2048;   // 0..1023
                int token0 = row0 + wrow + i * 16 + quad * 4;
                int bb     = token0 >> 12;
                float bv   = bias[bcol0 + wcol + j * 16 + n16];
                size_t vrow = ((size_t)bb * NHEAD + (dg >> 6)) * HD + (dg & 63);
                bf16x4 pk;
#pragma unroll
                for (int r = 0; r < 4; r++) pk[r] = (__bf16)(acc[i][j][r] + bv);
                *(bf16x4*)&VtOut[vrow * SEQ + (token0 & (SEQ - 1))] = pk;
            }
        }
    }
}

// ---------------------------------------------------------------------------
// fp32 -> bf16 casts
// ---------------------------------------------------------------------------
__global__ __launch_bounds__(256)
void cast_x(const float* __restrict__ s, bf16_t* __restrict__ d)
{
    size_t i = ((size_t)blockIdx.x * 256 + threadIdx.x) * 8;
    float4 a = *(const float4*)(s + i);
    float4 b = *(const float4*)(s + i + 4);
    bfrag o;
    o[0] = (__bf16)a.x; o[1] = (__bf16)a.y; o[2] = (__bf16)a.z; o[3] = (__bf16)a.w;
    o[4] = (__bf16)b.x; o[5] = (__bf16)b.y; o[6] = (__bf16)b.z; o[7] = (__bf16)b.w;
    *(bfrag*)(d + i) = o;
}

__global__ __launch_bounds__(256)
void cast_w(const float* __restrict__ wq, const float* __restrict__ wk,
            const float* __restrict__ wv, const float* __restrict__ wo,
            bf16_t* __restrict__ d)   // d = [Wq*0.125|Wk|Wv|Wo] bf16
{
    size_t t   = (size_t)blockIdx.x * 256 + threadIdx.x;   // 0..524287
    int    sel = (int)(t >> 17);
    const float* s = sel == 0 ? wq : (sel == 1 ? wk : (sel == 2 ? wv : wo));
    const float sc = (sel == 0) ? 0.125f : 1.0f;   // pre-bake softmax scale into Wq
    size_t off = (t & 131071) * 8;
    float4 a = *(const float4*)(s + off);
    float4 b = *(const float4*)(s + off + 4);
    bfrag o;
    o[0] = (__bf16)(a.x * sc); o[1] = (__bf16)(a.y * sc);
    o[2] = (__bf16)(a.z * sc); o[3] = (__bf16)(a.w * sc);
    o[4] = (__bf16)(b.x * sc); o[5] = (__bf16)(b.y * sc);
    o[6] = (__bf16)(b.z * sc); o[7] = (__bf16)(b.w * sc);
    *(bfrag*)(d + (size_t)sel * 1048576 + off) = o;
}

// ---------------------------------------------------------------------------
// Flash sliding-window attention, transposed frame (S^T / O^T). Unchanged.
// ---------------------------------------------------------------------------
__global__ __launch_bounds__(256, 4)
void attn_win(const bf16_t* __restrict__ QK, const bf16_t* __restrict__ Vt,
              bf16_t* __restrict__ AO)
{
    __shared__ __align__(16) bf16_t Ks[2][64 * 72];     // 18432 B
    __shared__ __align__(16) bf16_t Pw[4][32 * PSTR];   // 19456 B, wave-private

    const int tid  = threadIdx.x;
    const int wid  = tid >> 6;          // 0..3
    const int lane = tid & 63;
    const int n16  = lane & 15;
    const int quad = lane >> 4;

    const int lin = blockIdx.x;          // 0..1023
    const int sub = lin >> 3;            // 0..127
    const int bh  = (lin & 7) * 4 + (sub >> 5);
    const int qt  = sub & 31;
    const int qb0 = qt * 128;

    const int b  = bh >> 4, h = bh & 15;
    const size_t bS   = (size_t)b * SEQ;
    const size_t hoff = (size_t)h * HD;
    const bf16_t* Vb  = Vt + (size_t)bh * HD * SEQ;   // [d][s]
    const int wstart  = qb0 - 512;
    const int it0     = (qb0 < 512) ? ((512 - qb0) >> 6) : 0;

    const int srow  = tid >> 2;
    const int scol0 = (tid & 3) * 16;

    const int qwmin = qb0 + wid * 32;
    const int qwmax = qwmin + 31;
    int qa[2];
    bfrag bq0[2], bq1[2];
#pragma unroll
    for (int qg = 0; qg < 2; qg++) {
        qa[qg] = qwmin + qg * 16 + n16;
        bq0[qg] = *(const bfrag*)(&QK[(bS + qa[qg]) * LQK + hoff + quad * 8]);
        bq1[qg] = *(const bfrag*)(&QK[(bS + qa[qg]) * LQK + hoff + 32 + quad * 8]);
    }

    f32x4 ao[2][4];
#pragma unroll
    for (int qg = 0; qg < 2; qg++)
#pragma unroll
        for (int j = 0; j < 4; j++) ao[qg][j] = (f32x4){0.f, 0.f, 0.f, 0.f};
    float m[2] = {-1e30f, -1e30f}, l[2] = {0.f, 0.f};

    uint4 kp0, kp1;
    {
        const bf16_t* src = &QK[(bS + wstart + it0 * 64 + srow) * LQK + 1024 + hoff + scol0];
        kp0 = *(const uint4*)(src);
        kp1 = *(const uint4*)(src + 8);
    }

    for (int it = it0; it < 10; ++it) {
        const int k0 = wstart + it * 64;
        const int pb = it & 1;
        *(uint4*)(&Ks[pb][srow * 72 + scol0])     = kp0;
        *(uint4*)(&Ks[pb][srow * 72 + scol0 + 8]) = kp1;
        __syncthreads();
        if (it < 9) {
            const bf16_t* src = &QK[(bS + wstart + (it + 1) * 64 + srow) * LQK + 1024 + hoff + scol0];
            kp0 = *(const uint4*)(src);
            kp1 = *(const uint4*)(src + 8);
        }

        if (k0 > qwmax || k0 + 63 < qwmin - 511) continue;

        f32x4 a[2][4];
#pragma unroll
        for (int nt = 0; nt < 4; nt++) {
            bfrag ak0 = *(const bfrag*)(&Ks[pb][(nt * 16 + n16) * 72 + quad * 8]);
            bfrag ak1 = *(const bfrag*)(&Ks[pb][(nt * 16 + n16) * 72 + 32 + quad * 8]);
#pragma unroll
            for (int qg = 0; qg < 2; qg++) {
                f32x4 s4 = (f32x4){0.f, 0.f, 0.f, 0.f};
                s4 = __builtin_amdgcn_mfma_f32_16x16x32_bf16(ak0, bq0[qg], s4, 0, 0, 0);
                s4 = __builtin_amdgcn_mfma_f32_16x16x32_bf16(ak1, bq1[qg], s4, 0, 0, 0);
                a[qg][nt] = s4;
            }
        }

#pragma unroll
        for (int qg = 0; qg < 2; qg++) {
            const int gmin = qwmin + qg * 16, gmax = gmin + 15;
            const bool msk = !((k0 >= gmax - 511) & (k0 + 63 <= gmin));
            if (msk) {
#pragma unroll
                for (int nt = 0; nt < 4; nt++)
#pragma unroll
                    for (int r = 0; r < 4; r++) {
                        int ka = k0 + nt * 16 + quad * 4 + r;
                        bool valid = (ka >= qa[qg] - 511) & (ka <= qa[qg]);
                        if (!valid) a[qg][nt][r] = -1e30f;
                    }
            }

            float cm = -1e30f;
#pragma unroll
            for (int nt = 0; nt < 4; nt++)
#pragma unroll
                for (int r = 0; r < 4; r++) cm = fmaxf(cm, a[qg][nt][r]);
            cm = fmaxf(cm, __shfl_xor(cm, 16, 64));
            cm = fmaxf(cm, __shfl_xor(cm, 32, 64));
            float mn    = fmaxf(m[qg], cm);
            float alpha = __expf(m[qg] - mn);
            m[qg] = mn;
#pragma unroll
            for (int j = 0; j < 4; j++)
#pragma unroll
                for (int r = 0; r < 4; r++) ao[qg][j][r] *= alpha;

            float lacc = 0.f;
#pragma unroll
            for (int nt = 0; nt < 4; nt++) {
                bf16x4 pk;
#pragma unroll
                for (int r = 0; r < 4; r++) {
                    float p = __expf(a[qg][nt][r] - m[qg]);
                    lacc += p;
                    pk[r] = (__bf16)p;
                }
                *(bf16x4*)&Pw[wid][(qg * 16 + n16) * PSTR + nt * 16 + quad * 4] = pk;
            }
            l[qg] = l[qg] * alpha + lacc;
        }

#pragma unroll
        for (int ks = 0; ks < 2; ks++) {
            bfrag bp[2];
#pragma unroll
            for (int qg = 0; qg < 2; qg++)
                bp[qg] = *(const bfrag*)(&Pw[wid][(qg * 16 + n16) * PSTR + ks * 32 + quad * 8]);
#pragma unroll
            for (int j = 0; j < 4; j++) {
                bfrag av = *(const bfrag*)(&Vb[(size_t)(j * 16 + n16) * SEQ
                                               + k0 + ks * 32 + quad * 8]);
#pragma unroll
                for (int qg = 0; qg < 2; qg++)
                    ao[qg][j] = __builtin_amdgcn_mfma_f32_16x16x32_bf16(av, bp[qg], ao[qg][j], 0, 0, 0);
            }
        }
    }

#pragma unroll
    for (int qg = 0; qg < 2; qg++) {
        float lv = l[qg];
        lv += __shfl_xor(lv, 16, 64);
        lv += __shfl_xor(lv, 32, 64);
        const float inv = 1.0f / lv;
#pragma unroll
        for (int j = 0; j < 4; j++) {
            bf16x4 pk;
#pragma unroll
            for (int r = 0; r < 4; r++) pk[r] = (__bf16)(ao[qg][j][r] * inv);
            *(bf16x4*)&AO[(bS + qa[qg]) * NDIM + hoff + j * 16 + quad * 4] = pk;
        }
    }
}

// ---------------------------------------------------------------------------
extern "C" void kernel_launch(void* const* d_in, const int* in_sizes, int n_in,
                              void* d_out, int out_size, void* d_ws, size_t ws_size,
                              hipStream_t stream)
{
    const float* x  = (const float*)d_in[0];
    const float* Wq = (const float*)d_in[1];
    const float* bq = (const float*)d_in[2];
    const float* Wk = (const float*)d_in[3];
    const float* bk = (const float*)d_in[4];
    const float* Wv = (const float*)d_in[5];
    const float* bv = (const float*)d_in[6];
    const float* Wo = (const float*)d_in[7];
    const float* bo = (const float*)d_in[8];
    float* out = (float*)d_out;

    const size_t QK_E = (size_t)MROWS * LQK;
    const size_t X_E  = (size_t)MROWS * NDIM;
    if (ws_size < (QK_E + X_E + 4u * 1048576u) * sizeof(bf16_t)) return;

    bf16_t* QKb = (bf16_t*)d_ws;
    bf16_t* AbX = QKb + QK_E;
    bf16_t* Wc  = AbX + X_E;
    bf16_t* Wob = Wc + 3u * 1048576u;
    bf16_t* Vtg = (bf16_t*)d_out;   // scratch inside out buf; dead before O-proj

    // one-time: allow 128 KiB dynamic LDS for gemm256 (host-side, capture-safe)
    static int lds_ok = -1;
    if (lds_ok < 0)
        lds_ok = (hipFuncSetAttribute((const void*)gemm256,
                   hipFuncAttributeMaxDynamicSharedMemorySize, 131072) == hipSuccess) ? 1 : 0;

    dim3 blk(256);

    cast_x<<<dim3(4096), blk, 0, stream>>>(x, AbX);
    cast_w<<<dim3(2048), blk, 0, stream>>>(Wq, Wk, Wv, Wo, Wc);

    if (lds_ok) {
        gemm256<<<dim3(3072 / 256, MROWS / 256), dim3(512), 131072, stream>>>(
            AbX, NDIM, Wc, bq, bk, bv, 0.125f, QKb, LQK, NDIM, Vtg);
    } else {
        gemm_bt<bf16_t><<<dim3(3072 / 128, MROWS / 128), blk, 0, stream>>>(
            AbX, NDIM, Wc, bq, bk, bv, 0.125f, QKb, LQK, NDIM, Vtg);
    }

    attn_win<<<dim3(1024), dim3(256), 0, stream>>>(QKb, Vtg, AbX);

    gemm_bt<float><<<dim3(NDIM / 128, MROWS / 128), blk, 0, stream>>>(
        AbX, NDIM, Wob, bo, bo, bo, 1.0f, out, NDIM, NDIM, nullptr);
}

// Round 5
// 265.820 us; speedup vs baseline: 1.0378x; 1.0378x over previous
//
#include <hip/hip_runtime.h>
#include <hip/hip_bf16.h>

typedef __bf16 bf16_t;
typedef __attribute__((ext_vector_type(8))) __bf16 bfrag;   // 8 bf16 = 4 VGPRs (MFMA A/B frag)
typedef __attribute__((ext_vector_type(4))) __bf16 bf16x4;  // 8B packed store
typedef __attribute__((ext_vector_type(4))) float f32x4;    // MFMA C/D frag

#define SEQ    4096
#define NDIM   1024
#define NHEAD  16
#define HD     64
#define NBATCH 2
#define MROWS  (NBATCH * SEQ)   // 8192
#define LQK    2048             // fused Q|K row stride
#define PSTR   76               // Pw key-stride (conflict-free b64 writes)

// async 16B global -> LDS (m97 pattern). l must be wave-uniform; lane i lands at l + i*16.
__device__ __forceinline__ void gload_lds16(const bf16_t* g, bf16_t* l) {
    __builtin_amdgcn_global_load_lds(
        (const __attribute__((address_space(1))) unsigned int*)g,
        (__attribute__((address_space(3))) unsigned int*)l,
        16, 0, 0);
}

// raw workgroup barrier WITHOUT the vmcnt(0)/lgkmcnt(0) drain of __syncthreads.
__device__ __forceinline__ void block_sync() {
    asm volatile("" ::: "memory");
    __builtin_amdgcn_s_barrier();
    asm volatile("" ::: "memory");
}
#define VMC(n)  asm volatile("s_waitcnt vmcnt(" #n ")" ::: "memory")

// stage 8 KiB (128 rows x 64 B) of a [*, 32-el] LDS region: linear DMA dest,
// pre-swizzled global source (swizzle byte ^= ((byte>>9)&1)<<5). half=0 -> rows
// 0..127, half=1 -> rows 128..255. One gload_lds16 per thread per call.
// (R1-verified verbatim; R2's precomputed-pointer refactor of this was the bug.)
__device__ __forceinline__ void stage_half(const bf16_t* __restrict__ G, int ldg,
                                           int grow0, int gk0, bf16_t* region,
                                           int half, int tid)
{
    const int poff = half * 8192 + tid * 16;            // dest byte in region (linear)
    const int loff = poff ^ (((poff >> 9) & 1) << 5);   // logical byte (pre-swizzled src)
    const int r    = loff >> 6;                         // row (64 B rows)
    const int cb   = loff & 63;
    const bf16_t* src = G + (size_t)(grow0 + r) * ldg + gk0 + (cb >> 1);
    gload_lds16(src, region + ((half * 8192 + (tid >> 6) * 1024) >> 1));
}

__device__ __forceinline__ bfrag ldsfrag(const bf16_t* region, int R, int quad)
{
    const int off = (R * 64 + quad * 16) ^ (((R >> 3) & 1) << 5);   // bytes
    return *(const bfrag*)((const char*)region + off);
}

// ---------------------------------------------------------------------------
// 2-phase 256xBN GEMM (R1-verified structure; best measured schedule for this
// problem shape -- three deeper-pipelined variants all measured equal/slower).
//   C[M,N] = A[M,K] @ W[N,K]^T + bias; V-range (col>=2048) written transposed.
// 512 thr / 8 waves (2M x 4N), per-wave 128 x BN/4 out, BK=32, LDS double-buf
// = 2*(8192 + BN*32) els (64 KiB @BN=256, 48 KiB @BN=128). Zero bank conflicts
// (R1/R3 PMC). Flat grid + bijective XCD swizzle (nwg%8==0): each XCD owns a
// contiguous row-chunk -> A panel working set 2 MB fits per-XCD L2.
// vmcnt ledger (1 load/thread per stage_half call, NBH = BN/128 calls per B):
//   prologue: A0(2)+B0(NBH)+B1(NBH) issued; wait A0+B0 -> VMC(NBH).
//   end ph2(t): queue = [B(t+1) NBH, A(t+1) 2, B(t+2) NBH]; next ph1 reads
//   A(t+1),B(t+1) -> VMC(NBH); tail t>=nt-2 -> VMC(0).
// ---------------------------------------------------------------------------
template <int BN, typename OT>
__global__ __launch_bounds__(512, 2)
void gemm2ph(const bf16_t* __restrict__ A, int lda,
             const bf16_t* __restrict__ W,
             const float* __restrict__ b0p, const float* __restrict__ b1p,
             const float* __restrict__ b2p, float qscale,
             OT* __restrict__ C, int ldc, int K,
             bf16_t* __restrict__ VtOut, int nbx)
{
    constexpr int JR   = BN / 64;     // B j-frags per wave (4 @256, 2 @128)
    constexpr int NBH  = BN / 128;    // stage_half calls per B tile (2 / 1)
    constexpr int ABUF = 8192;        // A els per buf (256 rows x 32)
    constexpr int BBUF = BN * 32;     // B els per buf
    constexpr int BUF  = ABUF + BBUF;
    __shared__ __align__(1024) bf16_t LSD[2 * BUF];

    const int tid  = threadIdx.x;
    const int lane = tid & 63;
    const int n16  = lane & 15;
    const int quad = lane >> 4;
    const int wid  = tid >> 6;
    const int wm   = wid >> 2;            // 0..1
    const int wn   = wid & 3;             // 0..3

    // bijective XCD swizzle (nwg % 8 == 0 for both grids used)
    const int nwg = (int)gridDim.x;
    const int f   = (int)blockIdx.x;
    const int swz = (f & 7) * (nwg >> 3) + (f >> 3);
    const int bx  = swz % nbx;
    const int by  = swz / nbx;
    const int row0 = by * 256;
    const int col0 = bx * BN;
    const int nt   = K >> 5;              // K-tiles of 32

    f32x4 acc[8][JR];
#pragma unroll
    for (int m = 0; m < 8; m++)
#pragma unroll
        for (int j = 0; j < JR; j++) acc[m][j] = (f32x4){0.f, 0.f, 0.f, 0.f};

    // ---- prologue: A(0), B(0) -> buf0; B(1) -> buf1 (A(1) staged at t=0 ph1)
    {
        bf16_t* A0 = &LSD[0];
        bf16_t* B0 = &LSD[ABUF];
        bf16_t* B1 = &LSD[BUF + ABUF];
        stage_half(A, lda, row0, 0, A0, 0, tid);
        stage_half(A, lda, row0, 0, A0, 1, tid);
        stage_half(W, K, col0, 0, B0, 0, tid);
        if constexpr (NBH == 2) stage_half(W, K, col0, 0, B0, 1, tid);
        stage_half(W, K, col0, 32, B1, 0, tid);
        if constexpr (NBH == 2) stage_half(W, K, col0, 32, B1, 1, tid);
    }
    if constexpr (NBH == 2) { VMC(2); } else { VMC(1); }

    for (int t = 0; t < nt; ++t) {
        bf16_t* Ab  = &LSD[(t & 1) * BUF];
        bf16_t* Bb  = Ab + ABUF;
        bf16_t* AbN = &LSD[((t & 1) ^ 1) * BUF];

        bfrag a[4], b[JR];

        // ---- phase 1: A-lo x B(all) ----
        block_sync();
#pragma unroll
        for (int m = 0; m < 4; m++) a[m] = ldsfrag(Ab, wm * 128 + m * 16 + n16, quad);
#pragma unroll
        for (int j = 0; j < JR; j++) b[j] = ldsfrag(Bb, wn * (BN / 4) + j * 16 + n16, quad);
        if (t + 1 < nt) {   // A region of other buf: last read ph2(t-1), >=1 barrier ago
            stage_half(A, lda, row0, (t + 1) * 32, AbN, 0, tid);
            stage_half(A, lda, row0, (t + 1) * 32, AbN, 1, tid);
        }
        asm volatile("s_waitcnt lgkmcnt(0)" ::: "memory");
        __builtin_amdgcn_sched_barrier(0);
        __builtin_amdgcn_s_setprio(1);
#pragma unroll
        for (int m = 0; m < 4; m++)
#pragma unroll
            for (int j = 0; j < JR; j++)
                acc[m][j] = __builtin_amdgcn_mfma_f32_16x16x32_bf16(a[m], b[j], acc[m][j], 0, 0, 0);
        __builtin_amdgcn_s_setprio(0);

        // ---- phase 2: A-hi x B(all) ----
        block_sync();
#pragma unroll
        for (int m = 0; m < 4; m++) a[m] = ldsfrag(Ab, wm * 128 + (m + 4) * 16 + n16, quad);
        if (t + 2 < nt) {   // B region of this buf freed at ph1 (one barrier ago)
            stage_half(W, K, col0, (t + 2) * 32, Bb, 0, tid);
            if constexpr (NBH == 2) stage_half(W, K, col0, (t + 2) * 32, Bb, 1, tid);
        }
        asm volatile("s_waitcnt lgkmcnt(0)" ::: "memory");
        __builtin_amdgcn_sched_barrier(0);
        __builtin_amdgcn_s_setprio(1);
#pragma unroll
        for (int m = 0; m < 4; m++)
#pragma unroll
            for (int j = 0; j < JR; j++)
                acc[m + 4][j] = __builtin_amdgcn_mfma_f32_16x16x32_bf16(a[m], b[j], acc[m + 4][j], 0, 0, 0);
        __builtin_amdgcn_s_setprio(0);

        // counted checkpoint (see ledger above)
        if (t < nt - 2) { if constexpr (NBH == 2) { VMC(2); } else { VMC(1); } }
        else            { VMC(0); }
    }

    // ---- epilogue ----
    const float* bias = (col0 < 1024) ? b0p : (col0 < 2048 ? b1p : b2p);
    const float bsc   = (col0 < 1024) ? qscale : 1.0f;
    const int bcol0   = col0 & 1023;

    if (col0 < 2048 || VtOut == nullptr) {
#pragma unroll
        for (int m = 0; m < 8; m++)
#pragma unroll
            for (int j = 0; j < JR; j++)
#pragma unroll
                for (int r = 0; r < 4; r++) {
                    int row = row0 + wm * 128 + m * 16 + quad * 4 + r;
                    int col = wn * (BN / 4) + j * 16 + n16;
                    float v = acc[m][j][r] + bias[bcol0 + col] * bsc;
                    C[(size_t)row * ldc + col0 + col] = (OT)v;
                }
    } else {
        // V block: write transposed into Vt[(b*16+h)*64+d][s], packed 4 tokens
#pragma unroll
        for (int m = 0; m < 8; m++) {
#pragma unroll
            for (int j = 0; j < JR; j++) {
                int dg     = col0 + wn * (BN / 4) + j * 16 + n16 - 2048;   // 0..1023
                int token0 = row0 + wm * 128 + m * 16 + quad * 4;
                int bb     = token0 >> 12;
                float bv   = bias[bcol0 + wn * (BN / 4) + j * 16 + n16];
                size_t vrow = ((size_t)bb * NHEAD + (dg >> 6)) * HD + (dg & 63);
                bf16x4 pk;
#pragma unroll
                for (int r = 0; r < 4; r++) pk[r] = (__bf16)(acc[m][j][r] + bv);
                *(bf16x4*)&VtOut[vrow * SEQ + (token0 & (SEQ - 1))] = pk;
            }
        }
    }
}

// ---------------------------------------------------------------------------
// fp32 -> bf16 casts
// ---------------------------------------------------------------------------
__global__ __launch_bounds__(256)
void cast_x(const float* __restrict__ s, bf16_t* __restrict__ d)
{
    size_t i = ((size_t)blockIdx.x * 256 + threadIdx.x) * 8;
    float4 a = *(const float4*)(s + i);
    float4 b = *(const float4*)(s + i + 4);
    bfrag o;
    o[0] = (__bf16)a.x; o[1] = (__bf16)a.y; o[2] = (__bf16)a.z; o[3] = (__bf16)a.w;
    o[4] = (__bf16)b.x; o[5] = (__bf16)b.y; o[6] = (__bf16)b.z; o[7] = (__bf16)b.w;
    *(bfrag*)(d + i) = o;
}

__global__ __launch_bounds__(256)
void cast_w(const float* __restrict__ wq, const float* __restrict__ wk,
            const float* __restrict__ wv, const float* __restrict__ wo,
            bf16_t* __restrict__ d)   // d = [Wq*0.125|Wk|Wv|Wo] bf16
{
    size_t t   = (size_t)blockIdx.x * 256 + threadIdx.x;   // 0..524287
    int    sel = (int)(t >> 17);
    const float* s = sel == 0 ? wq : (sel == 1 ? wk : (sel == 2 ? wv : wo));
    const float sc = (sel == 0) ? 0.125f : 1.0f;   // pre-bake softmax scale into Wq
    size_t off = (t & 131071) * 8;
    float4 a = *(const float4*)(s + off);
    float4 b = *(const float4*)(s + off + 4);
    bfrag o;
    o[0] = (__bf16)(a.x * sc); o[1] = (__bf16)(a.y * sc);
    o[2] = (__bf16)(a.z * sc); o[3] = (__bf16)(a.w * sc);
    o[4] = (__bf16)(b.x * sc); o[5] = (__bf16)(b.y * sc);
    o[6] = (__bf16)(b.z * sc); o[7] = (__bf16)(b.w * sc);
    *(bfrag*)(d + (size_t)sel * 1048576 + off) = o;
}

// ---------------------------------------------------------------------------
// Flash sliding-window attention, transposed frame (S^T / O^T). Unchanged.
// ---------------------------------------------------------------------------
__global__ __launch_bounds__(256, 4)
void attn_win(const bf16_t* __restrict__ QK, const bf16_t* __restrict__ Vt,
              bf16_t* __restrict__ AO)
{
    __shared__ __align__(16) bf16_t Ks[2][64 * 72];     // 18432 B
    __shared__ __align__(16) bf16_t Pw[4][32 * PSTR];   // 19456 B, wave-private

    const int tid  = threadIdx.x;
    const int wid  = tid >> 6;          // 0..3
    const int lane = tid & 63;
    const int n16  = lane & 15;
    const int quad = lane >> 4;

    const int lin = blockIdx.x;          // 0..1023
    const int sub = lin >> 3;            // 0..127
    const int bh  = (lin & 7) * 4 + (sub >> 5);
    const int qt  = sub & 31;
    const int qb0 = qt * 128;

    const int b  = bh >> 4, h = bh & 15;
    const size_t bS   = (size_t)b * SEQ;
    const size_t hoff = (size_t)h * HD;
    const bf16_t* Vb  = Vt + (size_t)bh * HD * SEQ;   // [d][s]
    const int wstart  = qb0 - 512;
    const int it0     = (qb0 < 512) ? ((512 - qb0) >> 6) : 0;

    const int srow  = tid >> 2;
    const int scol0 = (tid & 3) * 16;

    const int qwmin = qb0 + wid * 32;
    const int qwmax = qwmin + 31;
    int qa[2];
    bfrag bq0[2], bq1[2];
#pragma unroll
    for (int qg = 0; qg < 2; qg++) {
        qa[qg] = qwmin + qg * 16 + n16;
        bq0[qg] = *(const bfrag*)(&QK[(bS + qa[qg]) * LQK + hoff + quad * 8]);
        bq1[qg] = *(const bfrag*)(&QK[(bS + qa[qg]) * LQK + hoff + 32 + quad * 8]);
    }

    f32x4 ao[2][4];
#pragma unroll
    for (int qg = 0; qg < 2; qg++)
#pragma unroll
        for (int j = 0; j < 4; j++) ao[qg][j] = (f32x4){0.f, 0.f, 0.f, 0.f};
    float m[2] = {-1e30f, -1e30f}, l[2] = {0.f, 0.f};

    uint4 kp0, kp1;
    {
        const bf16_t* src = &QK[(bS + wstart + it0 * 64 + srow) * LQK + 1024 + hoff + scol0];
        kp0 = *(const uint4*)(src);
        kp1 = *(const uint4*)(src + 8);
    }

    for (int it = it0; it < 10; ++it) {
        const int k0 = wstart + it * 64;
        const int pb = it & 1;
        *(uint4*)(&Ks[pb][srow * 72 + scol0])     = kp0;
        *(uint4*)(&Ks[pb][srow * 72 + scol0 + 8]) = kp1;
        __syncthreads();
        if (it < 9) {
            const bf16_t* src = &QK[(bS + wstart + (it + 1) * 64 + srow) * LQK + 1024 + hoff + scol0];
            kp0 = *(const uint4*)(src);
            kp1 = *(const uint4*)(src + 8);
        }

        if (k0 > qwmax || k0 + 63 < qwmin - 511) continue;

        f32x4 a[2][4];
#pragma unroll
        for (int nt = 0; nt < 4; nt++) {
            bfrag ak0 = *(const bfrag*)(&Ks[pb][(nt * 16 + n16) * 72 + quad * 8]);
            bfrag ak1 = *(const bfrag*)(&Ks[pb][(nt * 16 + n16) * 72 + 32 + quad * 8]);
#pragma unroll
            for (int qg = 0; qg < 2; qg++) {
                f32x4 s4 = (f32x4){0.f, 0.f, 0.f, 0.f};
                s4 = __builtin_amdgcn_mfma_f32_16x16x32_bf16(ak0, bq0[qg], s4, 0, 0, 0);
                s4 = __builtin_amdgcn_mfma_f32_16x16x32_bf16(ak1, bq1[qg], s4, 0, 0, 0);
                a[qg][nt] = s4;
            }
        }

#pragma unroll
        for (int qg = 0; qg < 2; qg++) {
            const int gmin = qwmin + qg * 16, gmax = gmin + 15;
            const bool msk = !((k0 >= gmax - 511) & (k0 + 63 <= gmin));
            if (msk) {
#pragma unroll
                for (int nt = 0; nt < 4; nt++)
#pragma unroll
                    for (int r = 0; r < 4; r++) {
                        int ka = k0 + nt * 16 + quad * 4 + r;
                        bool valid = (ka >= qa[qg] - 511) & (ka <= qa[qg]);
                        if (!valid) a[qg][nt][r] = -1e30f;
                    }
            }

            float cm = -1e30f;
#pragma unroll
            for (int nt = 0; nt < 4; nt++)
#pragma unroll
                for (int r = 0; r < 4; r++) cm = fmaxf(cm, a[qg][nt][r]);
            cm = fmaxf(cm, __shfl_xor(cm, 16, 64));
            cm = fmaxf(cm, __shfl_xor(cm, 32, 64));
            float mn    = fmaxf(m[qg], cm);
            float alpha = __expf(m[qg] - mn);
            m[qg] = mn;
#pragma unroll
            for (int j = 0; j < 4; j++)
#pragma unroll
                for (int r = 0; r < 4; r++) ao[qg][j][r] *= alpha;

            float lacc = 0.f;
#pragma unroll
            for (int nt = 0; nt < 4; nt++) {
                bf16x4 pk;
#pragma unroll
                for (int r = 0; r < 4; r++) {
                    float p = __expf(a[qg][nt][r] - m[qg]);
                    lacc += p;
                    pk[r] = (__bf16)p;
                }
                *(bf16x4*)&Pw[wid][(qg * 16 + n16) * PSTR + nt * 16 + quad * 4] = pk;
            }
            l[qg] = l[qg] * alpha + lacc;
        }

#pragma unroll
        for (int ks = 0; ks < 2; ks++) {
            bfrag bp[2];
#pragma unroll
            for (int qg = 0; qg < 2; qg++)
                bp[qg] = *(const bfrag*)(&Pw[wid][(qg * 16 + n16) * PSTR + ks * 32 + quad * 8]);
#pragma unroll
            for (int j = 0; j < 4; j++) {
                bfrag av = *(const bfrag*)(&Vb[(size_t)(j * 16 + n16) * SEQ
                                               + k0 + ks * 32 + quad * 8]);
#pragma unroll
                for (int qg = 0; qg < 2; qg++)
                    ao[qg][j] = __builtin_amdgcn_mfma_f32_16x16x32_bf16(av, bp[qg], ao[qg][j], 0, 0, 0);
            }
        }
    }

#pragma unroll
    for (int qg = 0; qg < 2; qg++) {
        float lv = l[qg];
        lv += __shfl_xor(lv, 16, 64);
        lv += __shfl_xor(lv, 32, 64);
        const float inv = 1.0f / lv;
#pragma unroll
        for (int j = 0; j < 4; j++) {
            bf16x4 pk;
#pragma unroll
            for (int r = 0; r < 4; r++) pk[r] = (__bf16)(ao[qg][j][r] * inv);
            *(bf16x4*)&AO[(bS + qa[qg]) * NDIM + hoff + j * 16 + quad * 4] = pk;
        }
    }
}

// ---------------------------------------------------------------------------
extern "C" void kernel_launch(void* const* d_in, const int* in_sizes, int n_in,
                              void* d_out, int out_size, void* d_ws, size_t ws_size,
                              hipStream_t stream)
{
    const float* x  = (const float*)d_in[0];
    const float* Wq = (const float*)d_in[1];
    const float* bq = (const float*)d_in[2];
    const float* Wk = (const float*)d_in[3];
    const float* bk = (const float*)d_in[4];
    const float* Wv = (const float*)d_in[5];
    const float* bv = (const float*)d_in[6];
    const float* Wo = (const float*)d_in[7];
    const float* bo = (const float*)d_in[8];
    float* out = (float*)d_out;

    const size_t QK_E = (size_t)MROWS * LQK;
    const size_t X_E  = (size_t)MROWS * NDIM;
    if (ws_size < (QK_E + X_E + 4u * 1048576u) * sizeof(bf16_t)) return;

    bf16_t* QKb = (bf16_t*)d_ws;
    bf16_t* AbX = QKb + QK_E;
    bf16_t* Wc  = AbX + X_E;
    bf16_t* Wob = Wc + 3u * 1048576u;
    bf16_t* Vtg = (bf16_t*)d_out;   // scratch inside out buf; dead before O-proj

    dim3 blk(256);

    cast_x<<<dim3(4096), blk, 0, stream>>>(x, AbX);
    cast_w<<<dim3(2048), blk, 0, stream>>>(Wq, Wk, Wv, Wo, Wc);

    // fused QKV projection: 2-phase 256x256 (R1-verified) + XCD swizzle.
    // grid 384 = 12 col-blocks x 32 row-blocks, flat; 384 % 8 == 0.
    gemm2ph<256, bf16_t><<<dim3(384), dim3(512), 0, stream>>>(
        AbX, NDIM, Wc, bq, bk, bv, 0.125f, QKb, LQK, NDIM, Vtg, 12);

    attn_win<<<dim3(1024), dim3(256), 0, stream>>>(QKb, Vtg, AbX);

    // output projection: 2-phase 256x128 (grid 256 = 8 x 32, exactly 1 round).
    gemm2ph<128, float><<<dim3(256), dim3(512), 0, stream>>>(
        AbX, NDIM, Wob, bo, bo, bo, 1.0f, out, NDIM, NDIM, nullptr, 8);
}

// Round 6
// 253.737 us; speedup vs baseline: 1.0872x; 1.0476x over previous
//
#include <hip/hip_runtime.h>
#include <hip/hip_bf16.h>

typedef __bf16 bf16_t;
typedef __attribute__((ext_vector_type(8))) __bf16 bfrag;   // 8 bf16 = 4 VGPRs (MFMA A/B frag)
typedef __attribute__((ext_vector_type(4))) __bf16 bf16x4;  // 8B packed store
typedef __attribute__((ext_vector_type(4))) float f32x4;    // MFMA C/D frag

#define SEQ    4096
#define NDIM   1024
#define NHEAD  16
#define HD     64
#define NBATCH 2
#define MROWS  (NBATCH * SEQ)   // 8192
#define LQK    2048             // fused Q|K row stride
#define PSTR   76               // Pw key-stride (conflict-free b64 writes)

// async 16B global -> LDS (m97 pattern). l must be wave-uniform; lane i lands at l + i*16.
__device__ __forceinline__ void gload_lds16(const bf16_t* g, bf16_t* l) {
    __builtin_amdgcn_global_load_lds(
        (const __attribute__((address_space(1))) unsigned int*)g,
        (__attribute__((address_space(3))) unsigned int*)l,
        16, 0, 0);
}

// raw workgroup barrier WITHOUT the vmcnt(0)/lgkmcnt(0) drain of __syncthreads.
__device__ __forceinline__ void block_sync() {
    asm volatile("" ::: "memory");
    __builtin_amdgcn_s_barrier();
    asm volatile("" ::: "memory");
}
#define VMC(n)  asm volatile("s_waitcnt vmcnt(" #n ")" ::: "memory")

// stage 8 KiB (128 rows x 64 B) of a [*, 32-el] LDS region: linear DMA dest,
// pre-swizzled global source (swizzle byte ^= ((byte>>9)&1)<<5). half=0 -> rows
// 0..127, half=1 -> rows 128..255. One gload_lds16 per thread per call (512 thr).
// (R1/R5-verified verbatim.)
__device__ __forceinline__ void stage_half(const bf16_t* __restrict__ G, int ldg,
                                           int grow0, int gk0, bf16_t* region,
                                           int half, int tid)
{
    const int poff = half * 8192 + tid * 16;            // dest byte in region (linear)
    const int loff = poff ^ (((poff >> 9) & 1) << 5);   // logical byte (pre-swizzled src)
    const int r    = loff >> 6;                         // row (64 B rows)
    const int cb   = loff & 63;
    const bf16_t* src = G + (size_t)(grow0 + r) * ldg + gk0 + (cb >> 1);
    gload_lds16(src, region + ((half * 8192 + (tid >> 6) * 1024) >> 1));
}

__device__ __forceinline__ bfrag ldsfrag(const bf16_t* region, int R, int quad)
{
    const int off = (R * 64 + quad * 16) ^ (((R >> 3) & 1) << 5);   // bytes
    return *(const bfrag*)((const char*)region + off);
}

// ---------------------------------------------------------------------------
// 2-phase 128x256 GEMM, 2 blocks/CU (R6).  C = A[M,K] @ W[N,K]^T + bias.
// Rationale: four schedule variants (m97-128^2, 2ph-256^2, two 8-phase) all
// pinned at ~670 TF at 1-2 blocks/CU-equivalent; m97's 912 TF came from
// IMPLICIT CROSS-BLOCK overlap at ~3 blocks/CU (stalls of one block hide
// under another's compute). This keeps the R5-verified 2-phase counted-vmcnt
// schedule but shrinks the tile: BM=128, 48 KiB LDS, acc[4][4] -> 2 blocks/CU
// (launch_bounds(512,4): 4 waves/EU => VGPR<=128; LDS 2x48=96<=160 KiB).
// 512 thr / 8 waves (2M x 4N), per-wave 64x64 out, BK=32.
// vmcnt ledger (per-tile loads A:1 + B:2):
//   prologue: A0(1)+B0(2)+B1(2); wait A0,B0 -> VMC(2).
//   end ph2(t): queue = [B(t+1):2, A(t+1):1, B(t+2):2]; next ph1 reads
//   A(t+1),B(t+1) -> VMC(2); t>=nt-2 -> VMC(0).
// WAR: identical publication scheme to R5 (stage lands >=1 barrier after the
// dest region's last read, whose lgkmcnt(0) precedes that phase's MFMA).
// Grid flat + bijective XCD swizzle (nwg%8==0): XCD owns contiguous row-chunk.
// ---------------------------------------------------------------------------
template <typename OT>
__global__ __launch_bounds__(512, 4)
void gemm2ph(const bf16_t* __restrict__ A, int lda,
             const bf16_t* __restrict__ W,
             const float* __restrict__ b0p, const float* __restrict__ b1p,
             const float* __restrict__ b2p, float qscale,
             OT* __restrict__ C, int ldc, int K,
             bf16_t* __restrict__ VtOut, int nbx)
{
    constexpr int ABUF = 4096;        // A els per buf (128 rows x 32)
    constexpr int BBUF = 8192;        // B els per buf (256 rows x 32)
    constexpr int BUF  = ABUF + BBUF;
    __shared__ __align__(1024) bf16_t LSD[2 * BUF];   // 48 KiB

    const int tid  = threadIdx.x;
    const int lane = tid & 63;
    const int n16  = lane & 15;
    const int quad = lane >> 4;
    const int wid  = tid >> 6;
    const int wm   = wid >> 2;            // 0..1 (64-row half)
    const int wn   = wid & 3;             // 0..3 (64-col quarter)

    // bijective XCD swizzle (nwg % 8 == 0 for both grids used)
    const int nwg = (int)gridDim.x;
    const int f   = (int)blockIdx.x;
    const int swz = (f & 7) * (nwg >> 3) + (f >> 3);
    const int bx  = swz % nbx;
    const int by  = swz / nbx;
    const int row0 = by * 128;
    const int col0 = bx * 256;
    const int nt   = K >> 5;              // K-tiles of 32 (nt >= 3)

    f32x4 acc[4][4];
#pragma unroll
    for (int m = 0; m < 4; m++)
#pragma unroll
        for (int j = 0; j < 4; j++) acc[m][j] = (f32x4){0.f, 0.f, 0.f, 0.f};

    // ---- prologue: A(0), B(0) -> buf0; B(1) -> buf1 (A(1) staged at t=0 ph1)
    {
        bf16_t* A0 = &LSD[0];
        bf16_t* B0 = &LSD[ABUF];
        bf16_t* B1 = &LSD[BUF + ABUF];
        stage_half(A, lda, row0, 0, A0, 0, tid);
        stage_half(W, K, col0, 0, B0, 0, tid);
        stage_half(W, K, col0, 0, B0, 1, tid);
        stage_half(W, K, col0, 32, B1, 0, tid);
        stage_half(W, K, col0, 32, B1, 1, tid);
    }
    VMC(2);   // A0,B0 landed (per wave); barrier at ph1 publishes across waves

    for (int t = 0; t < nt; ++t) {
        bf16_t* Ab  = &LSD[(t & 1) * BUF];
        bf16_t* Bb  = Ab + ABUF;
        bf16_t* AbN = &LSD[((t & 1) ^ 1) * BUF];

        bfrag a[2], b[4];

        // ---- phase 1: A rows 0-31 of wave half x B(all) ----
        block_sync();
#pragma unroll
        for (int m = 0; m < 2; m++) a[m] = ldsfrag(Ab, wm * 64 + m * 16 + n16, quad);
#pragma unroll
        for (int j = 0; j < 4; j++) b[j] = ldsfrag(Bb, wn * 64 + j * 16 + n16, quad);
        if (t + 1 < nt)   // A region of other buf: last read ph2(t-1), >=1 barrier ago
            stage_half(A, lda, row0, (t + 1) * 32, AbN, 0, tid);
        asm volatile("s_waitcnt lgkmcnt(0)" ::: "memory");
        __builtin_amdgcn_sched_barrier(0);
        __builtin_amdgcn_s_setprio(1);
#pragma unroll
        for (int m = 0; m < 2; m++)
#pragma unroll
            for (int j = 0; j < 4; j++)
                acc[m][j] = __builtin_amdgcn_mfma_f32_16x16x32_bf16(a[m], b[j], acc[m][j], 0, 0, 0);
        __builtin_amdgcn_s_setprio(0);

        // ---- phase 2: A rows 32-63 of wave half x B(all) ----
        block_sync();
#pragma unroll
        for (int m = 0; m < 2; m++) a[m] = ldsfrag(Ab, wm * 64 + (m + 2) * 16 + n16, quad);
        if (t + 2 < nt) {   // B region of this buf freed at ph1 (one barrier ago)
            stage_half(W, K, col0, (t + 2) * 32, Bb, 0, tid);
            stage_half(W, K, col0, (t + 2) * 32, Bb, 1, tid);
        }
        asm volatile("s_waitcnt lgkmcnt(0)" ::: "memory");
        __builtin_amdgcn_sched_barrier(0);
        __builtin_amdgcn_s_setprio(1);
#pragma unroll
        for (int m = 0; m < 2; m++)
#pragma unroll
            for (int j = 0; j < 4; j++)
                acc[m + 2][j] = __builtin_amdgcn_mfma_f32_16x16x32_bf16(a[m], b[j], acc[m + 2][j], 0, 0, 0);
        __builtin_amdgcn_s_setprio(0);

        // counted checkpoint (see ledger above)
        if (t < nt - 2) { VMC(2); }
        else            { VMC(0); }
    }

    // ---- epilogue ----
    const float* bias = (col0 < 1024) ? b0p : (col0 < 2048 ? b1p : b2p);
    const float bsc   = (col0 < 1024) ? qscale : 1.0f;
    const int bcol0   = col0 & 1023;

    if (col0 < 2048 || VtOut == nullptr) {
#pragma unroll
        for (int m = 0; m < 4; m++)
#pragma unroll
            for (int j = 0; j < 4; j++)
#pragma unroll
                for (int r = 0; r < 4; r++) {
                    int row = row0 + wm * 64 + m * 16 + quad * 4 + r;
                    int col = wn * 64 + j * 16 + n16;
                    float v = acc[m][j][r] + bias[bcol0 + col] * bsc;
                    C[(size_t)row * ldc + col0 + col] = (OT)v;
                }
    } else {
        // V block: write transposed into Vt[(b*16+h)*64+d][s], packed 4 tokens
#pragma unroll
        for (int m = 0; m < 4; m++) {
#pragma unroll
            for (int j = 0; j < 4; j++) {
                int dg     = col0 + wn * 64 + j * 16 + n16 - 2048;   // 0..1023
                int token0 = row0 + wm * 64 + m * 16 + quad * 4;
                int bb     = token0 >> 12;
                float bv   = bias[bcol0 + wn * 64 + j * 16 + n16];
                size_t vrow = ((size_t)bb * NHEAD + (dg >> 6)) * HD + (dg & 63);
                bf16x4 pk;
#pragma unroll
                for (int r = 0; r < 4; r++) pk[r] = (__bf16)(acc[m][j][r] + bv);
                *(bf16x4*)&VtOut[vrow * SEQ + (token0 & (SEQ - 1))] = pk;
            }
        }
    }
}

// ---------------------------------------------------------------------------
// fp32 -> bf16 casts
// ---------------------------------------------------------------------------
__global__ __launch_bounds__(256)
void cast_x(const float* __restrict__ s, bf16_t* __restrict__ d)
{
    size_t i = ((size_t)blockIdx.x * 256 + threadIdx.x) * 8;
    float4 a = *(const float4*)(s + i);
    float4 b = *(const float4*)(s + i + 4);
    bfrag o;
    o[0] = (__bf16)a.x; o[1] = (__bf16)a.y; o[2] = (__bf16)a.z; o[3] = (__bf16)a.w;
    o[4] = (__bf16)b.x; o[5] = (__bf16)b.y; o[6] = (__bf16)b.z; o[7] = (__bf16)b.w;
    *(bfrag*)(d + i) = o;
}

__global__ __launch_bounds__(256)
void cast_w(const float* __restrict__ wq, const float* __restrict__ wk,
            const float* __restrict__ wv, const float* __restrict__ wo,
            bf16_t* __restrict__ d)   // d = [Wq*0.125|Wk|Wv|Wo] bf16
{
    size_t t   = (size_t)blockIdx.x * 256 + threadIdx.x;   // 0..524287
    int    sel = (int)(t >> 17);
    const float* s = sel == 0 ? wq : (sel == 1 ? wk : (sel == 2 ? wv : wo));
    const float sc = (sel == 0) ? 0.125f : 1.0f;   // pre-bake softmax scale into Wq
    size_t off = (t & 131071) * 8;
    float4 a = *(const float4*)(s + off);
    float4 b = *(const float4*)(s + off + 4);
    bfrag o;
    o[0] = (__bf16)(a.x * sc); o[1] = (__bf16)(a.y * sc);
    o[2] = (__bf16)(a.z * sc); o[3] = (__bf16)(a.w * sc);
    o[4] = (__bf16)(b.x * sc); o[5] = (__bf16)(b.y * sc);
    o[6] = (__bf16)(b.z * sc); o[7] = (__bf16)(b.w * sc);
    *(bfrag*)(d + (size_t)sel * 1048576 + off) = o;
}

// ---------------------------------------------------------------------------
// Flash sliding-window attention, transposed frame (S^T / O^T). Unchanged.
// ---------------------------------------------------------------------------
__global__ __launch_bounds__(256, 4)
void attn_win(const bf16_t* __restrict__ QK, const bf16_t* __restrict__ Vt,
              bf16_t* __restrict__ AO)
{
    __shared__ __align__(16) bf16_t Ks[2][64 * 72];     // 18432 B
    __shared__ __align__(16) bf16_t Pw[4][32 * PSTR];   // 19456 B, wave-private

    const int tid  = threadIdx.x;
    const int wid  = tid >> 6;          // 0..3
    const int lane = tid & 63;
    const int n16  = lane & 15;
    const int quad = lane >> 4;

    const int lin = blockIdx.x;          // 0..1023
    const int sub = lin >> 3;            // 0..127
    const int bh  = (lin & 7) * 4 + (sub >> 5);
    const int qt  = sub & 31;
    const int qb0 = qt * 128;

    const int b  = bh >> 4, h = bh & 15;
    const size_t bS   = (size_t)b * SEQ;
    const size_t hoff = (size_t)h * HD;
    const bf16_t* Vb  = Vt + (size_t)bh * HD * SEQ;   // [d][s]
    const int wstart  = qb0 - 512;
    const int it0     = (qb0 < 512) ? ((512 - qb0) >> 6) : 0;

    const int srow  = tid >> 2;
    const int scol0 = (tid & 3) * 16;

    const int qwmin = qb0 + wid * 32;
    const int qwmax = qwmin + 31;
    int qa[2];
    bfrag bq0[2], bq1[2];
#pragma unroll
    for (int qg = 0; qg < 2; qg++) {
        qa[qg] = qwmin + qg * 16 + n16;
        bq0[qg] = *(const bfrag*)(&QK[(bS + qa[qg]) * LQK + hoff + quad * 8]);
        bq1[qg] = *(const bfrag*)(&QK[(bS + qa[qg]) * LQK + hoff + 32 + quad * 8]);
    }

    f32x4 ao[2][4];
#pragma unroll
    for (int qg = 0; qg < 2; qg++)
#pragma unroll
        for (int j = 0; j < 4; j++) ao[qg][j] = (f32x4){0.f, 0.f, 0.f, 0.f};
    float m[2] = {-1e30f, -1e30f}, l[2] = {0.f, 0.f};

    uint4 kp0, kp1;
    {
        const bf16_t* src = &QK[(bS + wstart + it0 * 64 + srow) * LQK + 1024 + hoff + scol0];
        kp0 = *(const uint4*)(src);
        kp1 = *(const uint4*)(src + 8);
    }

    for (int it = it0; it < 10; ++it) {
        const int k0 = wstart + it * 64;
        const int pb = it & 1;
        *(uint4*)(&Ks[pb][srow * 72 + scol0])     = kp0;
        *(uint4*)(&Ks[pb][srow * 72 + scol0 + 8]) = kp1;
        __syncthreads();
        if (it < 9) {
            const bf16_t* src = &QK[(bS + wstart + (it + 1) * 64 + srow) * LQK + 1024 + hoff + scol0];
            kp0 = *(const uint4*)(src);
            kp1 = *(const uint4*)(src + 8);
        }

        if (k0 > qwmax || k0 + 63 < qwmin - 511) continue;

        f32x4 a[2][4];
#pragma unroll
        for (int nt = 0; nt < 4; nt++) {
            bfrag ak0 = *(const bfrag*)(&Ks[pb][(nt * 16 + n16) * 72 + quad * 8]);
            bfrag ak1 = *(const bfrag*)(&Ks[pb][(nt * 16 + n16) * 72 + 32 + quad * 8]);
#pragma unroll
            for (int qg = 0; qg < 2; qg++) {
                f32x4 s4 = (f32x4){0.f, 0.f, 0.f, 0.f};
                s4 = __builtin_amdgcn_mfma_f32_16x16x32_bf16(ak0, bq0[qg], s4, 0, 0, 0);
                s4 = __builtin_amdgcn_mfma_f32_16x16x32_bf16(ak1, bq1[qg], s4, 0, 0, 0);
                a[qg][nt] = s4;
            }
        }

#pragma unroll
        for (int qg = 0; qg < 2; qg++) {
            const int gmin = qwmin + qg * 16, gmax = gmin + 15;
            const bool msk = !((k0 >= gmax - 511) & (k0 + 63 <= gmin));
            if (msk) {
#pragma unroll
                for (int nt = 0; nt < 4; nt++)
#pragma unroll
                    for (int r = 0; r < 4; r++) {
                        int ka = k0 + nt * 16 + quad * 4 + r;
                        bool valid = (ka >= qa[qg] - 511) & (ka <= qa[qg]);
                        if (!valid) a[qg][nt][r] = -1e30f;
                    }
            }

            float cm = -1e30f;
#pragma unroll
            for (int nt = 0; nt < 4; nt++)
#pragma unroll
                for (int r = 0; r < 4; r++) cm = fmaxf(cm, a[qg][nt][r]);
            cm = fmaxf(cm, __shfl_xor(cm, 16, 64));
            cm = fmaxf(cm, __shfl_xor(cm, 32, 64));
            float mn    = fmaxf(m[qg], cm);
            float alpha = __expf(m[qg] - mn);
            m[qg] = mn;
#pragma unroll
            for (int j = 0; j < 4; j++)
#pragma unroll
                for (int r = 0; r < 4; r++) ao[qg][j][r] *= alpha;

            float lacc = 0.f;
#pragma unroll
            for (int nt = 0; nt < 4; nt++) {
                bf16x4 pk;
#pragma unroll
                for (int r = 0; r < 4; r++) {
                    float p = __expf(a[qg][nt][r] - m[qg]);
                    lacc += p;
                    pk[r] = (__bf16)p;
                }
                *(bf16x4*)&Pw[wid][(qg * 16 + n16) * PSTR + nt * 16 + quad * 4] = pk;
            }
            l[qg] = l[qg] * alpha + lacc;
        }

#pragma unroll
        for (int ks = 0; ks < 2; ks++) {
            bfrag bp[2];
#pragma unroll
            for (int qg = 0; qg < 2; qg++)
                bp[qg] = *(const bfrag*)(&Pw[wid][(qg * 16 + n16) * PSTR + ks * 32 + quad * 8]);
#pragma unroll
            for (int j = 0; j < 4; j++) {
                bfrag av = *(const bfrag*)(&Vb[(size_t)(j * 16 + n16) * SEQ
                                               + k0 + ks * 32 + quad * 8]);
#pragma unroll
                for (int qg = 0; qg < 2; qg++)
                    ao[qg][j] = __builtin_amdgcn_mfma_f32_16x16x32_bf16(av, bp[qg], ao[qg][j], 0, 0, 0);
            }
        }
    }

#pragma unroll
    for (int qg = 0; qg < 2; qg++) {
        float lv = l[qg];
        lv += __shfl_xor(lv, 16, 64);
        lv += __shfl_xor(lv, 32, 64);
        const float inv = 1.0f / lv;
#pragma unroll
        for (int j = 0; j < 4; j++) {
            bf16x4 pk;
#pragma unroll
            for (int r = 0; r < 4; r++) pk[r] = (__bf16)(ao[qg][j][r] * inv);
            *(bf16x4*)&AO[(bS + qa[qg]) * NDIM + hoff + j * 16 + quad * 4] = pk;
        }
    }
}

// ---------------------------------------------------------------------------
extern "C" void kernel_launch(void* const* d_in, const int* in_sizes, int n_in,
                              void* d_out, int out_size, void* d_ws, size_t ws_size,
                              hipStream_t stream)
{
    const float* x  = (const float*)d_in[0];
    const float* Wq = (const float*)d_in[1];
    const float* bq = (const float*)d_in[2];
    const float* Wk = (const float*)d_in[3];
    const float* bk = (const float*)d_in[4];
    const float* Wv = (const float*)d_in[5];
    const float* bv = (const float*)d_in[6];
    const float* Wo = (const float*)d_in[7];
    const float* bo = (const float*)d_in[8];
    float* out = (float*)d_out;

    const size_t QK_E = (size_t)MROWS * LQK;
    const size_t X_E  = (size_t)MROWS * NDIM;
    if (ws_size < (QK_E + X_E + 4u * 1048576u) * sizeof(bf16_t)) return;

    bf16_t* QKb = (bf16_t*)d_ws;
    bf16_t* AbX = QKb + QK_E;
    bf16_t* Wc  = AbX + X_E;
    bf16_t* Wob = Wc + 3u * 1048576u;
    bf16_t* Vtg = (bf16_t*)d_out;   // scratch inside out buf; dead before O-proj

    dim3 blk(256);

    cast_x<<<dim3(4096), blk, 0, stream>>>(x, AbX);
    cast_w<<<dim3(2048), blk, 0, stream>>>(Wq, Wk, Wv, Wo, Wc);

    // fused QKV projection: 2-phase 128x256, 2 blocks/CU.
    // grid 768 = 64 row-blocks x 12 col-blocks, flat; 768 % 8 == 0.
    gemm2ph<bf16_t><<<dim3(768), dim3(512), 0, stream>>>(
        AbX, NDIM, Wc, bq, bk, bv, 0.125f, QKb, LQK, NDIM, Vtg, 12);

    attn_win<<<dim3(1024), dim3(256), 0, stream>>>(QKb, Vtg, AbX);

    // output projection: 2-phase 128x256 (grid 256 = 64 x 4, fully resident).
    gemm2ph<float><<<dim3(256), dim3(512), 0, stream>>>(
        AbX, NDIM, Wob, bo, bo, bo, 1.0f, out, NDIM, NDIM, nullptr, 4);
}